// Round 4
// baseline (54.569 us; speedup 1.0000x reference)
//
#include <hip/hip_runtime.h>

#define EPSF 1e-7f

__device__ __forceinline__ float rcp_fast(float x) { return __builtin_amdgcn_rcpf(x); }

// LDS tile swizzle: float4 chunk index XORed with row bits 2..4.
// Chosen so the Gram's xjv read (rows = tx*4+b, tx = lane&15) spreads the 16
// distinct row-addresses across 8 bank-groups (2-way aliasing = free).
__device__ __forceinline__ int swz(int r, int c) { return r * 16 + (c ^ ((r >> 2) & 7)); }

// K1: x2[j] = ||x_j||^2
__global__ __launch_bounds__(64) void x2_kernel(const float* __restrict__ x, float* __restrict__ x2) {
    int j = blockIdx.x * 64 + threadIdx.x;
    const float4* row = reinterpret_cast<const float4*>(x + (size_t)j * 64);
    float s = 0.f;
#pragma unroll
    for (int c = 0; c < 16; ++c) {
        float4 v = row[c];
        s += v.x * v.x + v.y * v.y + v.z * v.z + v.w * v.w;
    }
    x2[j] = s;
}

// K2: 64x64 tile per block, 4x4 micro-tile per thread. Both x-tiles staged in
// LDS (contiguous 16KB chunks of x -> coalesced), Gram from LDS, scalar map,
// T[i,j] out + alpha partials per j-tile.
__global__ __launch_bounds__(256) void pair_kernel(
    const float* __restrict__ x, const int* __restrict__ adj,
    const float* __restrict__ x2ws, float* __restrict__ T,
    float* __restrict__ alphaPart) {
    const int N = 1024;
    const int j0 = blockIdx.x * 64;
    const int i0 = blockIdx.y * 64;
    const int t = threadIdx.x;
    const int tx = t & 15;   // j quad
    const int ty = t >> 4;   // i quad

    __shared__ float4 ti[1024];  // 16 KB
    __shared__ float4 tj[1024];  // 16 KB

    const float4* x4 = reinterpret_cast<const float4*>(x);
#pragma unroll
    for (int k = 0; k < 4; ++k) {
        const int fl = k * 256 + t;
        const int r = fl >> 4, c = fl & 15;
        ti[swz(r, c)] = x4[(size_t)i0 * 16 + fl];
        tj[swz(r, c)] = x4[(size_t)j0 * 16 + fl];
    }
    __syncthreads();

    float acc[4][4];
#pragma unroll
    for (int a = 0; a < 4; ++a)
#pragma unroll
        for (int b = 0; b < 4; ++b) acc[a][b] = 0.f;

#pragma unroll
    for (int c = 0; c < 16; ++c) {
        float4 xiv[4], xjv[4];
#pragma unroll
        for (int a = 0; a < 4; ++a) xiv[a] = ti[swz(ty * 4 + a, c)];
#pragma unroll
        for (int b = 0; b < 4; ++b) xjv[b] = tj[swz(tx * 4 + b, c)];
#pragma unroll
        for (int a = 0; a < 4; ++a)
#pragma unroll
            for (int b = 0; b < 4; ++b) {
                acc[a][b] = fmaf(xiv[a].x, xjv[b].x, acc[a][b]);
                acc[a][b] = fmaf(xiv[a].y, xjv[b].y, acc[a][b]);
                acc[a][b] = fmaf(xiv[a].z, xjv[b].z, acc[a][b]);
                acc[a][b] = fmaf(xiv[a].w, xjv[b].w, acc[a][b]);
            }
    }

    const int ib = i0 + ty * 4;
    const int jb = j0 + tx * 4;
    const float4 x2iv = *reinterpret_cast<const float4*>(&x2ws[ib]);
    const float4 y2v = *reinterpret_cast<const float4*>(&x2ws[jb]);
    const float x2i[4] = {x2iv.x, x2iv.y, x2iv.z, x2iv.w};
    const float y2[4] = {y2v.x, y2v.y, y2v.z, y2v.w};

    float svsum[4];
#pragma unroll
    for (int a = 0; a < 4; ++a) {
        const int4 aj = *reinterpret_cast<const int4*>(&adj[(size_t)(ib + a) * N + jb]);
        const int m[4] = {aj.x, aj.y, aj.z, aj.w};
        const float onemx2 = 1.f - x2i[a];
        const float onemx2c = fmaxf(onemx2, EPSF);
        float tv4[4];
        float ssum = 0.f;
#pragma unroll
        for (int b = 0; b < 4; ++b) {
            const float dot = acc[a][b];
            const float c1 = fmaf(-2.f, dot, 1.f);
            const float A = c1 + y2[b];
            const float den = fmaxf(fmaf(x2i[a], y2[b], c1), EPSF);
            const float rd = rcp_fast(den);
            const float av = -A * rd;
            const float bv = onemx2 * rd;
            float un2 = av * av * x2i[a];
            un2 = fmaf(bv * bv, y2[b], un2);
            un2 = fmaf(2.f * av * bv, dot, un2);
            un2 = fmaxf(un2, 0.f);
            float un = sqrtf(un2);
            un = fminf(fmaxf(un, EPSF), 1.0f - 1e-5f);
            const float ratio = (1.f + un) * rcp_fast(1.f - un);
            const float at = 0.34657359027997264f * __log2f(ratio);  // atanh(un)
            const float g = onemx2c * at * rcp_fast(un);
            const float sv = m[b] ? g * av : 0.f;
            const float tv = m[b] ? g * bv : 0.f;
            ssum += sv;
            tv4[b] = tv;
        }
        float4 tw = {tv4[0], tv4[1], tv4[2], tv4[3]};
        *reinterpret_cast<float4*>(&T[(size_t)(ib + a) * N + jb]) = tw;
        svsum[a] = ssum;
    }

    // reduce alpha over tx (lane bits 0..3)
#pragma unroll
    for (int off = 1; off <= 8; off <<= 1) {
#pragma unroll
        for (int a = 0; a < 4; ++a) svsum[a] += __shfl_xor(svsum[a], off, 64);
    }
    if (tx == 0) {
        float4 av = {svsum[0], svsum[1], svsum[2], svsum[3]};
        *reinterpret_cast<float4*>(&alphaPart[(size_t)blockIdx.x * N + ib]) = av;
    }
}

// K3: one wave per row i: v = T[i,:]*X, + alpha*x_i, expmap. j-loop unrolled
// so loads pipeline across iterations.
__global__ __launch_bounds__(256) void out_kernel(
    const float* __restrict__ x, const float* __restrict__ T,
    const float* __restrict__ alphaPart, const float* __restrict__ x2ws,
    float* __restrict__ out) {
    const int N = 1024, D = 64;
    const int w = threadIdx.x >> 6;
    const int d = threadIdx.x & 63;
    const int i = blockIdx.x * 4 + w;

    const float xid = x[(size_t)i * D + d];
    const float x2i = x2ws[i];
    const float onemx2 = 1.f - x2i;
    const float onemx2c = fmaxf(onemx2, EPSF);

    const float4* Tr = reinterpret_cast<const float4*>(T + (size_t)i * N);
    float v0 = 0.f, v1 = 0.f, v2 = 0.f, v3 = 0.f;
#pragma unroll 4
    for (int jb = 0; jb < 256; jb += 4) {  // 16 j per iteration
        float4 t0 = Tr[jb + 0];
        float4 t1 = Tr[jb + 1];
        float4 t2 = Tr[jb + 2];
        float4 t3 = Tr[jb + 3];
        const float* xp = x + (size_t)jb * 4 * D + d;
        v0 = fmaf(t0.x, xp[0 * D], v0);
        v1 = fmaf(t0.y, xp[1 * D], v1);
        v2 = fmaf(t0.z, xp[2 * D], v2);
        v3 = fmaf(t0.w, xp[3 * D], v3);
        v0 = fmaf(t1.x, xp[4 * D], v0);
        v1 = fmaf(t1.y, xp[5 * D], v1);
        v2 = fmaf(t1.z, xp[6 * D], v2);
        v3 = fmaf(t1.w, xp[7 * D], v3);
        v0 = fmaf(t2.x, xp[8 * D], v0);
        v1 = fmaf(t2.y, xp[9 * D], v1);
        v2 = fmaf(t2.z, xp[10 * D], v2);
        v3 = fmaf(t2.w, xp[11 * D], v3);
        v0 = fmaf(t3.x, xp[12 * D], v0);
        v1 = fmaf(t3.y, xp[13 * D], v1);
        v2 = fmaf(t3.z, xp[14 * D], v2);
        v3 = fmaf(t3.w, xp[15 * D], v3);
    }
    float v = (v0 + v1) + (v2 + v3);

    // alpha = sum of 16 j-tile partials
    float ap = (d < 16) ? alphaPart[(size_t)d * N + i] : 0.f;
#pragma unroll
    for (int off = 1; off < 64; off <<= 1) ap += __shfl_xor(ap, off, 64);
    v = fmaf(ap, xid, v);

    // expmap(v, x_i)
    float vn2 = v * v;
#pragma unroll
    for (int off = 1; off < 64; off <<= 1) vn2 += __shfl_xor(vn2, off, 64);
    const float vn = fmaxf(sqrtf(vn2), EPSF);
    const float arg = vn * rcp_fast(onemx2c);
    const float th = tanhf(arg);
    const float sec = th * rcp_fast(vn) * v;

    // mobius_add(x_i, sec)
    float xy = xid * sec;
    float y2p = sec * sec;
#pragma unroll
    for (int off = 1; off < 64; off <<= 1) {
        xy += __shfl_xor(xy, off, 64);
        y2p += __shfl_xor(y2p, off, 64);
    }
    const float numd = (1.f + 2.f * xy + y2p) * xid + onemx2 * sec;
    const float den2 = fmaxf(fmaf(x2i, y2p, 1.f + 2.f * xy), EPSF);
    out[(size_t)i * D + d] = numd * rcp_fast(den2);
}

extern "C" void kernel_launch(void* const* d_in, const int* in_sizes, int n_in,
                              void* d_out, int out_size, void* d_ws, size_t ws_size,
                              hipStream_t stream) {
    const float* x = (const float*)d_in[0];
    const int* adj = (const int*)d_in[1];
    float* out = (float*)d_out;
    const int N = 1024;

    float* T = (float*)d_ws;                                       // 4 MB
    float* alphaPart = (float*)((char*)d_ws + (size_t)N * N * 4);  // 64 KB
    float* x2 = (float*)((char*)d_ws + (size_t)N * N * 4 + 16 * N * 4);

    hipLaunchKernelGGL(x2_kernel, dim3(N / 64), dim3(64), 0, stream, x, x2);
    hipLaunchKernelGGL(pair_kernel, dim3(16, 16), dim3(256), 0, stream, x, adj, x2, T, alphaPart);
    hipLaunchKernelGGL(out_kernel, dim3(N / 4), dim3(256), 0, stream, x, T, alphaPart, x2, out);
}

// Round 5
// 27.502 us; speedup vs baseline: 1.9842x; 1.9842x over previous
//
#include <hip/hip_runtime.h>

#define EPSF 1e-7f

__device__ __forceinline__ float rcp_fast(float x) { return __builtin_amdgcn_rcpf(x); }

// LDS float4-chunk swizzle: spreads strided row reads across bank groups.
__device__ __forceinline__ int swz(int r, int c) { return r * 16 + (c ^ ((r >> 2) & 7)); }

// K1: x2[j] = ||x_j||^2
__global__ __launch_bounds__(64) void x2_kernel(const float* __restrict__ x, float* __restrict__ x2) {
    int j = blockIdx.x * 64 + threadIdx.x;
    const float4* row = reinterpret_cast<const float4*>(x + (size_t)j * 64);
    float s = 0.f;
#pragma unroll
    for (int c = 0; c < 16; ++c) {
        float4 v = row[c];
        s += v.x * v.x + v.y * v.y + v.z * v.z + v.w * v.w;
    }
    x2[j] = s;
}

// K2: 32(i) x 64(j) tile per block (512 blocks -> 2 blocks/CU), 2x4 micro-tile.
// Both x-tiles staged in LDS (coalesced), Gram from LDS, scalar map -> T + alpha.
__global__ __launch_bounds__(256) void pair_kernel(
    const float* __restrict__ x, const int* __restrict__ adj,
    const float* __restrict__ x2ws, float* __restrict__ T,
    float* __restrict__ alphaPart) {
    const int N = 1024;
    const int j0 = blockIdx.x * 64;   // 16 j-tiles
    const int i0 = blockIdx.y * 32;   // 32 i-tiles
    const int t = threadIdx.x;
    const int tx = t & 15;   // j quad
    const int ty = t >> 4;   // i pair index 0..15

    __shared__ float4 ti4[32 * 16];  // 8 KB
    __shared__ float4 tj4[64 * 16];  // 16 KB

    const float4* x4 = reinterpret_cast<const float4*>(x);
#pragma unroll
    for (int k = 0; k < 2; ++k) {
        const int f = k * 256 + t;
        ti4[swz(f >> 4, f & 15)] = x4[(size_t)i0 * 16 + f];
    }
#pragma unroll
    for (int k = 0; k < 4; ++k) {
        const int f = k * 256 + t;
        tj4[swz(f >> 4, f & 15)] = x4[(size_t)j0 * 16 + f];
    }
    __syncthreads();

    float acc[2][4];
#pragma unroll
    for (int a = 0; a < 2; ++a)
#pragma unroll
        for (int b = 0; b < 4; ++b) acc[a][b] = 0.f;

#pragma unroll
    for (int c = 0; c < 16; ++c) {
        float4 xiv[2], xjv[4];
#pragma unroll
        for (int a = 0; a < 2; ++a) xiv[a] = ti4[swz(ty * 2 + a, c)];
#pragma unroll
        for (int b = 0; b < 4; ++b) xjv[b] = tj4[swz(tx * 4 + b, c)];
#pragma unroll
        for (int a = 0; a < 2; ++a)
#pragma unroll
            for (int b = 0; b < 4; ++b) {
                acc[a][b] = fmaf(xiv[a].x, xjv[b].x, acc[a][b]);
                acc[a][b] = fmaf(xiv[a].y, xjv[b].y, acc[a][b]);
                acc[a][b] = fmaf(xiv[a].z, xjv[b].z, acc[a][b]);
                acc[a][b] = fmaf(xiv[a].w, xjv[b].w, acc[a][b]);
            }
    }

    const int ib = i0 + ty * 2;
    const int jb = j0 + tx * 4;
    const float x2i[2] = {x2ws[ib], x2ws[ib + 1]};
    const float4 y2v = *reinterpret_cast<const float4*>(&x2ws[jb]);
    const float y2[4] = {y2v.x, y2v.y, y2v.z, y2v.w};

    float svsum[2];
#pragma unroll
    for (int a = 0; a < 2; ++a) {
        const int4 aj = *reinterpret_cast<const int4*>(&adj[(size_t)(ib + a) * N + jb]);
        const int m[4] = {aj.x, aj.y, aj.z, aj.w};
        const float onemx2 = 1.f - x2i[a];
        const float onemx2c = fmaxf(onemx2, EPSF);
        float tv4[4];
        float ssum = 0.f;
#pragma unroll
        for (int b = 0; b < 4; ++b) {
            const float dot = acc[a][b];
            const float c1 = fmaf(-2.f, dot, 1.f);
            const float A = c1 + y2[b];
            const float den = fmaxf(fmaf(x2i[a], y2[b], c1), EPSF);
            const float rd = rcp_fast(den);
            const float av = -A * rd;
            const float bv = onemx2 * rd;
            float un2 = av * av * x2i[a];
            un2 = fmaf(bv * bv, y2[b], un2);
            un2 = fmaf(2.f * av * bv, dot, un2);
            un2 = fmaxf(un2, 0.f);
            float un = sqrtf(un2);
            un = fminf(fmaxf(un, EPSF), 1.0f - 1e-5f);
            const float ratio = (1.f + un) * rcp_fast(1.f - un);
            const float at = 0.34657359027997264f * __log2f(ratio);  // atanh(un)
            const float g = onemx2c * at * rcp_fast(un);
            const float sv = m[b] ? g * av : 0.f;
            const float tv = m[b] ? g * bv : 0.f;
            ssum += sv;
            tv4[b] = tv;
        }
        float4 tw = {tv4[0], tv4[1], tv4[2], tv4[3]};
        *reinterpret_cast<float4*>(&T[(size_t)(ib + a) * N + jb]) = tw;
        svsum[a] = ssum;
    }

    // reduce alpha over tx (lane bits 0..3)
#pragma unroll
    for (int off = 1; off <= 8; off <<= 1) {
#pragma unroll
        for (int a = 0; a < 2; ++a) svsum[a] += __shfl_xor(svsum[a], off, 64);
    }
    if (tx == 0) {
        alphaPart[(size_t)blockIdx.x * N + ib + 0] = svsum[0];
        alphaPart[(size_t)blockIdx.x * N + ib + 1] = svsum[1];
    }
}

// K3: block = 2 rows (512 blocks -> 2 blocks/CU). 4 waves split j into 256-chunks;
// T row bases readfirstlane'd -> scalar s_load path; x loads shared across rows.
__global__ __launch_bounds__(256) void out_kernel(
    const float* __restrict__ x, const float* __restrict__ T,
    const float* __restrict__ alphaPart, const float* __restrict__ x2ws,
    float* __restrict__ out) {
    const int N = 1024, D = 64;
    const int i0 = blockIdx.x * 2;
    const int w = threadIdx.x >> 6;
    const int d = threadIdx.x & 63;
    const int jw = __builtin_amdgcn_readfirstlane(w * 256);

    const float4* T0 = reinterpret_cast<const float4*>(T + (size_t)i0 * N + jw);
    const float4* T1 = reinterpret_cast<const float4*>(T + (size_t)(i0 + 1) * N + jw);
    const float* xbase = x + (size_t)jw * D + d;

    float a0 = 0.f, a1 = 0.f, a2 = 0.f, a3 = 0.f;
    float b0 = 0.f, b1 = 0.f, b2 = 0.f, b3 = 0.f;
#pragma unroll 4
    for (int q = 0; q < 64; ++q) {
        const float4 t0 = T0[q];
        const float4 t1 = T1[q];
        const float* xp = xbase + (size_t)q * 4 * D;
        const float x0 = xp[0 * D], x1v = xp[1 * D], x2v = xp[2 * D], x3v = xp[3 * D];
        a0 = fmaf(t0.x, x0, a0);  b0 = fmaf(t1.x, x0, b0);
        a1 = fmaf(t0.y, x1v, a1); b1 = fmaf(t1.y, x1v, b1);
        a2 = fmaf(t0.z, x2v, a2); b2 = fmaf(t1.z, x2v, b2);
        a3 = fmaf(t0.w, x3v, a3); b3 = fmaf(t1.w, x3v, b3);
    }
    const float va = (a0 + a1) + (a2 + a3);
    const float vb = (b0 + b1) + (b2 + b3);

    __shared__ float part[2][4][64];
    part[0][w][d] = va;
    part[1][w][d] = vb;
    __syncthreads();

    if (threadIdx.x < 128) {
        const int r = threadIdx.x >> 6;
        const int i = i0 + r;
        float v = (part[r][0][d] + part[r][1][d]) + (part[r][2][d] + part[r][3][d]);

        // alpha = sum of 16 j-tile partials
        float ap = (d < 16) ? alphaPart[(size_t)d * N + i] : 0.f;
#pragma unroll
        for (int off = 1; off < 64; off <<= 1) ap += __shfl_xor(ap, off, 64);

        const float x2i = x2ws[i];
        const float onemx2 = 1.f - x2i;
        const float onemx2c = fmaxf(onemx2, EPSF);
        const float xid = x[(size_t)i * D + d];
        v = fmaf(ap, xid, v);

        // expmap(v, x_i)
        float vn2 = v * v;
#pragma unroll
        for (int off = 1; off < 64; off <<= 1) vn2 += __shfl_xor(vn2, off, 64);
        const float vn = fmaxf(sqrtf(vn2), EPSF);
        const float arg = vn * rcp_fast(onemx2c);
        const float th = tanhf(arg);
        const float sec = th * rcp_fast(vn) * v;

        // mobius_add(x_i, sec)
        float xy = xid * sec;
        float y2p = sec * sec;
#pragma unroll
        for (int off = 1; off < 64; off <<= 1) {
            xy += __shfl_xor(xy, off, 64);
            y2p += __shfl_xor(y2p, off, 64);
        }
        const float numd = (1.f + 2.f * xy + y2p) * xid + onemx2 * sec;
        const float den2 = fmaxf(fmaf(x2i, y2p, 1.f + 2.f * xy), EPSF);
        out[(size_t)i * D + d] = numd * rcp_fast(den2);
    }
}

extern "C" void kernel_launch(void* const* d_in, const int* in_sizes, int n_in,
                              void* d_out, int out_size, void* d_ws, size_t ws_size,
                              hipStream_t stream) {
    const float* x = (const float*)d_in[0];
    const int* adj = (const int*)d_in[1];
    float* out = (float*)d_out;
    const int N = 1024;

    float* T = (float*)d_ws;                                       // 4 MB
    float* alphaPart = (float*)((char*)d_ws + (size_t)N * N * 4);  // 64 KB
    float* x2 = (float*)((char*)d_ws + (size_t)N * N * 4 + 16 * N * 4);

    hipLaunchKernelGGL(x2_kernel, dim3(N / 64), dim3(64), 0, stream, x, x2);
    hipLaunchKernelGGL(pair_kernel, dim3(16, 32), dim3(256), 0, stream, x, adj, x2, T, alphaPart);
    hipLaunchKernelGGL(out_kernel, dim3(N / 2), dim3(256), 0, stream, x, T, alphaPart, x2, out);
}

// Round 6
// 26.706 us; speedup vs baseline: 2.0433x; 1.0298x over previous
//
#include <hip/hip_runtime.h>

#define EPSF 1e-7f

__device__ __forceinline__ float rcp_fast(float x) { return __builtin_amdgcn_rcpf(x); }

// LDS float4-chunk swizzle: spreads strided row reads across bank groups.
__device__ __forceinline__ int swz(int r, int c) { return r * 16 + (c ^ ((r >> 2) & 7)); }

__device__ __forceinline__ float dot4(float4 v) {
    return v.x * v.x + v.y * v.y + v.z * v.z + v.w * v.w;
}

// K1: 32(i) x 64(j) tile per block (512 blocks), 4x4 micro-tile, 128 threads.
// x2 computed in-block from the staged register fragments. Outputs T + alphaPart.
__global__ __launch_bounds__(128) void pair_kernel(
    const float* __restrict__ x, const int* __restrict__ adj,
    float* __restrict__ T, float* __restrict__ alphaPart) {
    const int N = 1024;
    const int j0 = blockIdx.x * 64;   // 16 j-tiles
    const int i0 = blockIdx.y * 32;   // 32 i-tiles
    const int t = threadIdx.x;
    const int tx = t & 15;   // j quad (lane bits 0..3)
    const int ty = t >> 4;   // 0..7

    __shared__ float4 ti4[32 * 16];  // 8 KB
    __shared__ float4 tj4[64 * 16];  // 16 KB
    __shared__ float x2i_l[32];
    __shared__ float y2_l[64];

    const float4* x4 = reinterpret_cast<const float4*>(x);
    // stage + per-row norms from register fragments
#pragma unroll
    for (int k = 0; k < 4; ++k) {
        float4 v = x4[(size_t)i0 * 16 + k * 128 + t];
        ti4[swz(k * 8 + ty, tx)] = v;
        float s = dot4(v);
#pragma unroll
        for (int off = 1; off <= 8; off <<= 1) s += __shfl_xor(s, off, 64);
        if (tx == 0) x2i_l[k * 8 + ty] = s;
    }
#pragma unroll
    for (int k = 0; k < 8; ++k) {
        float4 v = x4[(size_t)j0 * 16 + k * 128 + t];
        tj4[swz(k * 8 + ty, tx)] = v;
        float s = dot4(v);
#pragma unroll
        for (int off = 1; off <= 8; off <<= 1) s += __shfl_xor(s, off, 64);
        if (tx == 0) y2_l[k * 8 + ty] = s;
    }
    __syncthreads();

    float acc[4][4];
#pragma unroll
    for (int a = 0; a < 4; ++a)
#pragma unroll
        for (int b = 0; b < 4; ++b) acc[a][b] = 0.f;

#pragma unroll
    for (int c = 0; c < 16; ++c) {
        float4 xiv[4], xjv[4];
#pragma unroll
        for (int a = 0; a < 4; ++a) xiv[a] = ti4[swz(ty * 4 + a, c)];
#pragma unroll
        for (int b = 0; b < 4; ++b) xjv[b] = tj4[swz(tx * 4 + b, c)];
#pragma unroll
        for (int a = 0; a < 4; ++a)
#pragma unroll
            for (int b = 0; b < 4; ++b) {
                acc[a][b] = fmaf(xiv[a].x, xjv[b].x, acc[a][b]);
                acc[a][b] = fmaf(xiv[a].y, xjv[b].y, acc[a][b]);
                acc[a][b] = fmaf(xiv[a].z, xjv[b].z, acc[a][b]);
                acc[a][b] = fmaf(xiv[a].w, xjv[b].w, acc[a][b]);
            }
    }

    const int ib = i0 + ty * 4;
    const int jb = j0 + tx * 4;
    const float4 y2v = *reinterpret_cast<const float4*>(&y2_l[tx * 4]);
    const float y2[4] = {y2v.x, y2v.y, y2v.z, y2v.w};
    const float4 x2iv = *reinterpret_cast<const float4*>(&x2i_l[ty * 4]);
    const float x2i[4] = {x2iv.x, x2iv.y, x2iv.z, x2iv.w};

    float svsum[4];
#pragma unroll
    for (int a = 0; a < 4; ++a) {
        const int4 aj = *reinterpret_cast<const int4*>(&adj[(size_t)(ib + a) * N + jb]);
        const int m[4] = {aj.x, aj.y, aj.z, aj.w};
        const float onemx2 = 1.f - x2i[a];
        const float onemx2c = fmaxf(onemx2, EPSF);
        float tv4[4];
        float ssum = 0.f;
#pragma unroll
        for (int b = 0; b < 4; ++b) {
            const float dot = acc[a][b];
            const float c1 = fmaf(-2.f, dot, 1.f);
            const float A = c1 + y2[b];
            const float den = fmaxf(fmaf(x2i[a], y2[b], c1), EPSF);
            const float rd = rcp_fast(den);
            const float av = -A * rd;
            const float bv = onemx2 * rd;
            float un2 = av * av * x2i[a];
            un2 = fmaf(bv * bv, y2[b], un2);
            un2 = fmaf(2.f * av * bv, dot, un2);
            un2 = fmaxf(un2, 0.f);
            float un = sqrtf(un2);
            un = fminf(fmaxf(un, EPSF), 1.0f - 1e-5f);
            const float ratio = (1.f + un) * rcp_fast(1.f - un);
            const float at = 0.34657359027997264f * __log2f(ratio);  // atanh(un)
            const float g = onemx2c * at * rcp_fast(un);
            const float sv = m[b] ? g * av : 0.f;
            const float tv = m[b] ? g * bv : 0.f;
            ssum += sv;
            tv4[b] = tv;
        }
        float4 tw = {tv4[0], tv4[1], tv4[2], tv4[3]};
        *reinterpret_cast<float4*>(&T[(size_t)(ib + a) * N + jb]) = tw;
        svsum[a] = ssum;
    }

    // reduce alpha over tx (lane bits 0..3)
#pragma unroll
    for (int off = 1; off <= 8; off <<= 1) {
#pragma unroll
        for (int a = 0; a < 4; ++a) svsum[a] += __shfl_xor(svsum[a], off, 64);
    }
    if (tx == 0) {
#pragma unroll
        for (int a = 0; a < 4; ++a)
            alphaPart[(size_t)blockIdx.x * N + ib + a] = svsum[a];
    }
}

// K2: block = 4 rows (256 blocks, 1/CU). 4 waves split j into 256-chunks;
// T row bases uniform (r compile-time, jw readfirstlane'd) -> scalar s_load path;
// each x load feeds 4 rows.
__global__ __launch_bounds__(256) void out_kernel(
    const float* __restrict__ x, const float* __restrict__ T,
    const float* __restrict__ alphaPart, float* __restrict__ out) {
    const int N = 1024, D = 64;
    const int i0 = blockIdx.x * 4;
    const int w = threadIdx.x >> 6;
    const int d = threadIdx.x & 63;
    const int jw = __builtin_amdgcn_readfirstlane(w * 256);

    const float4* T0 = reinterpret_cast<const float4*>(T + (size_t)(i0 + 0) * N + jw);
    const float4* T1 = reinterpret_cast<const float4*>(T + (size_t)(i0 + 1) * N + jw);
    const float4* T2 = reinterpret_cast<const float4*>(T + (size_t)(i0 + 2) * N + jw);
    const float4* T3 = reinterpret_cast<const float4*>(T + (size_t)(i0 + 3) * N + jw);
    const float* xbase = x + (size_t)jw * D + d;

    float acc[4][4];
#pragma unroll
    for (int r = 0; r < 4; ++r)
#pragma unroll
        for (int c = 0; c < 4; ++c) acc[r][c] = 0.f;

#pragma unroll 4
    for (int q = 0; q < 64; ++q) {
        const float4 tq[4] = {T0[q], T1[q], T2[q], T3[q]};
        const float* xp = xbase + (size_t)q * 4 * D;
        const float x0 = xp[0 * D], x1 = xp[1 * D], x2v = xp[2 * D], x3 = xp[3 * D];
#pragma unroll
        for (int r = 0; r < 4; ++r) {
            acc[r][0] = fmaf(tq[r].x, x0, acc[r][0]);
            acc[r][1] = fmaf(tq[r].y, x1, acc[r][1]);
            acc[r][2] = fmaf(tq[r].z, x2v, acc[r][2]);
            acc[r][3] = fmaf(tq[r].w, x3, acc[r][3]);
        }
    }

    __shared__ float part[4][4][64];
#pragma unroll
    for (int r = 0; r < 4; ++r)
        part[r][w][d] = (acc[r][0] + acc[r][1]) + (acc[r][2] + acc[r][3]);
    __syncthreads();

    {
        const int r = w;  // wave r handles row i0+r
        const int i = i0 + r;
        float v = (part[r][0][d] + part[r][1][d]) + (part[r][2][d] + part[r][3][d]);

        // alpha = sum of 16 j-tile partials
        float ap = (d < 16) ? alphaPart[(size_t)d * N + i] : 0.f;
#pragma unroll
        for (int off = 1; off < 64; off <<= 1) ap += __shfl_xor(ap, off, 64);

        const float xid = x[(size_t)i * D + d];
        float x2i = xid * xid;
#pragma unroll
        for (int off = 1; off < 64; off <<= 1) x2i += __shfl_xor(x2i, off, 64);
        const float onemx2 = 1.f - x2i;
        const float onemx2c = fmaxf(onemx2, EPSF);
        v = fmaf(ap, xid, v);

        // expmap(v, x_i)
        float vn2 = v * v;
#pragma unroll
        for (int off = 1; off < 64; off <<= 1) vn2 += __shfl_xor(vn2, off, 64);
        const float vn = fmaxf(sqrtf(vn2), EPSF);
        const float arg = vn * rcp_fast(onemx2c);
        const float th = tanhf(arg);
        const float sec = th * rcp_fast(vn) * v;

        // mobius_add(x_i, sec)
        float xy = xid * sec;
        float y2p = sec * sec;
#pragma unroll
        for (int off = 1; off < 64; off <<= 1) {
            xy += __shfl_xor(xy, off, 64);
            y2p += __shfl_xor(y2p, off, 64);
        }
        const float numd = (1.f + 2.f * xy + y2p) * xid + onemx2 * sec;
        const float den2 = fmaxf(fmaf(x2i, y2p, 1.f + 2.f * xy), EPSF);
        out[(size_t)i * D + d] = numd * rcp_fast(den2);
    }
}

extern "C" void kernel_launch(void* const* d_in, const int* in_sizes, int n_in,
                              void* d_out, int out_size, void* d_ws, size_t ws_size,
                              hipStream_t stream) {
    const float* x = (const float*)d_in[0];
    const int* adj = (const int*)d_in[1];
    float* out = (float*)d_out;
    const int N = 1024;

    float* T = (float*)d_ws;                                       // 4 MB
    float* alphaPart = (float*)((char*)d_ws + (size_t)N * N * 4);  // 64 KB

    hipLaunchKernelGGL(pair_kernel, dim3(16, 32), dim3(128), 0, stream, x, adj, T, alphaPart);
    hipLaunchKernelGGL(out_kernel, dim3(N / 4), dim3(256), 0, stream, x, T, alphaPart, out);
}

// Round 7
// 23.523 us; speedup vs baseline: 2.3198x; 1.1353x over previous
//
#include <hip/hip_runtime.h>

#define EPSF 1e-7f

__device__ __forceinline__ float rcp_fast(float x) { return __builtin_amdgcn_rcpf(x); }

// LDS float4-chunk swizzle: spreads strided row reads across bank groups.
__device__ __forceinline__ int swz(int r, int c) { return r * 16 + (c ^ ((r >> 2) & 7)); }

__device__ __forceinline__ float dot4(float4 v) {
    return v.x * v.x + v.y * v.y + v.z * v.z + v.w * v.w;
}

// K1: 32(i) x 64(j) tile per block, 512 blocks x 256 threads = 2 waves/SIMD.
// Lane-pair micro-tile: thread (q,h) computes 4x4 half-dots over dims [h*32,h*32+32),
// shfl_xor(1) combines; halves split the 16-pair scalar map (8 pairs each).
__global__ __launch_bounds__(256, 2) void pair_kernel(
    const float* __restrict__ x, const int* __restrict__ adj,
    float* __restrict__ T, float* __restrict__ alphaPart) {
    const int N = 1024;
    const int j0 = blockIdx.x * 64;
    const int i0 = blockIdx.y * 32;
    const int t = threadIdx.x;
    const int h = t & 1;     // dim half
    const int q = t >> 1;    // 0..127
    const int qx = q & 15;   // j quad
    const int qy = q >> 4;   // 0..7 i quad

    __shared__ float4 ti4[32 * 16];  // 8 KB
    __shared__ float4 tj4[64 * 16];  // 16 KB
    __shared__ float x2i_l[32];
    __shared__ float y2_l[64];

    const float4* x4 = reinterpret_cast<const float4*>(x);
#pragma unroll
    for (int k = 0; k < 2; ++k) {
        const int f = k * 256 + t;
        const int r = f >> 4, c = f & 15;
        float4 v = x4[(size_t)i0 * 16 + f];
        ti4[swz(r, c)] = v;
        float s = dot4(v);
#pragma unroll
        for (int off = 1; off <= 8; off <<= 1) s += __shfl_xor(s, off, 64);
        if ((t & 15) == 0) x2i_l[r] = s;
    }
#pragma unroll
    for (int k = 0; k < 4; ++k) {
        const int f = k * 256 + t;
        const int r = f >> 4, c = f & 15;
        float4 v = x4[(size_t)j0 * 16 + f];
        tj4[swz(r, c)] = v;
        float s = dot4(v);
#pragma unroll
        for (int off = 1; off <= 8; off <<= 1) s += __shfl_xor(s, off, 64);
        if ((t & 15) == 0) y2_l[r] = s;
    }
    __syncthreads();

    float acc[4][4];
#pragma unroll
    for (int a = 0; a < 4; ++a)
#pragma unroll
        for (int b = 0; b < 4; ++b) acc[a][b] = 0.f;

#pragma unroll
    for (int cc = 0; cc < 8; ++cc) {
        const int c = h * 8 + cc;
        float4 xiv[4], xjv[4];
#pragma unroll
        for (int a = 0; a < 4; ++a) xiv[a] = ti4[swz(qy * 4 + a, c)];
#pragma unroll
        for (int b = 0; b < 4; ++b) xjv[b] = tj4[swz(qx * 4 + b, c)];
#pragma unroll
        for (int a = 0; a < 4; ++a)
#pragma unroll
            for (int b = 0; b < 4; ++b) {
                acc[a][b] = fmaf(xiv[a].x, xjv[b].x, acc[a][b]);
                acc[a][b] = fmaf(xiv[a].y, xjv[b].y, acc[a][b]);
                acc[a][b] = fmaf(xiv[a].z, xjv[b].z, acc[a][b]);
                acc[a][b] = fmaf(xiv[a].w, xjv[b].w, acc[a][b]);
            }
    }
    // combine dim-halves: both lanes end with full 64-dim dots
#pragma unroll
    for (int a = 0; a < 4; ++a)
#pragma unroll
        for (int b = 0; b < 4; ++b) acc[a][b] += __shfl_xor(acc[a][b], 1, 64);

    const int ib = i0 + qy * 4;
    const int jb = j0 + qx * 4;
    const int bsel = h * 2;  // this half handles columns jb+bsel, jb+bsel+1
    const float y2[2] = {y2_l[qx * 4 + bsel], y2_l[qx * 4 + bsel + 1]};

    float svsum[4];
#pragma unroll
    for (int a = 0; a < 4; ++a) {
        const int2 aj = *reinterpret_cast<const int2*>(&adj[(size_t)(ib + a) * N + jb + bsel]);
        const int m[2] = {aj.x, aj.y};
        const float x2a = x2i_l[qy * 4 + a];
        const float onemx2 = 1.f - x2a;
        const float onemx2c = fmaxf(onemx2, EPSF);
        float tv2[2];
        float ssum = 0.f;
#pragma unroll
        for (int bb = 0; bb < 2; ++bb) {
            const float dot = acc[a][bsel + bb];
            const float c1 = fmaf(-2.f, dot, 1.f);
            const float A = c1 + y2[bb];
            const float den = fmaxf(fmaf(x2a, y2[bb], c1), EPSF);
            const float rd = rcp_fast(den);
            const float av = -A * rd;
            const float bv = onemx2 * rd;
            float un2 = av * av * x2a;
            un2 = fmaf(bv * bv, y2[bb], un2);
            un2 = fmaf(2.f * av * bv, dot, un2);
            un2 = fmaxf(un2, 0.f);
            float un = sqrtf(un2);
            un = fminf(fmaxf(un, EPSF), 1.0f - 1e-5f);
            const float ratio = (1.f + un) * rcp_fast(1.f - un);
            const float at = 0.34657359027997264f * __log2f(ratio);  // atanh(un)
            const float g = onemx2c * at * rcp_fast(un);
            const float sv = m[bb] ? g * av : 0.f;
            const float tv = m[bb] ? g * bv : 0.f;
            ssum += sv;
            tv2[bb] = tv;
        }
        float2 tw = {tv2[0], tv2[1]};
        *reinterpret_cast<float2*>(&T[(size_t)(ib + a) * N + jb + bsel]) = tw;
        svsum[a] = ssum;
    }

    // reduce alpha over lane bits 0..4 (h + qx)
#pragma unroll
    for (int off = 1; off <= 16; off <<= 1) {
#pragma unroll
        for (int a = 0; a < 4; ++a) svsum[a] += __shfl_xor(svsum[a], off, 64);
    }
    if ((t & 31) == 0) {
#pragma unroll
        for (int a = 0; a < 4; ++a)
            alphaPart[(size_t)blockIdx.x * N + ib + a] = svsum[a];
    }
}

// K2: block = 2 rows, 512 blocks x 256 thr = 2 waves/SIMD. 4 waves = j-quarters;
// scalar T bases (readfirstlane), each x load feeds both rows. LDS reduce + expmap.
__global__ __launch_bounds__(256, 2) void out_kernel(
    const float* __restrict__ x, const float* __restrict__ T,
    const float* __restrict__ alphaPart, float* __restrict__ out) {
    const int N = 1024, D = 64;
    const int i0 = blockIdx.x * 2;
    const int w = threadIdx.x >> 6;
    const int d = threadIdx.x & 63;
    const int jw = __builtin_amdgcn_readfirstlane(w * 256);

    const float4* T0 = reinterpret_cast<const float4*>(T + (size_t)i0 * N + jw);
    const float4* T1 = reinterpret_cast<const float4*>(T + (size_t)(i0 + 1) * N + jw);
    const float* xbase = x + (size_t)jw * D + d;

    float a0 = 0.f, a1 = 0.f, a2 = 0.f, a3 = 0.f;
    float b0 = 0.f, b1 = 0.f, b2 = 0.f, b3 = 0.f;
#pragma unroll 4
    for (int qq = 0; qq < 64; ++qq) {
        const float4 t0 = T0[qq];
        const float4 t1 = T1[qq];
        const float* xp = xbase + (size_t)qq * 4 * D;
        const float x0 = xp[0 * D], x1 = xp[1 * D], x2v = xp[2 * D], x3 = xp[3 * D];
        a0 = fmaf(t0.x, x0, a0);  b0 = fmaf(t1.x, x0, b0);
        a1 = fmaf(t0.y, x1, a1);  b1 = fmaf(t1.y, x1, b1);
        a2 = fmaf(t0.z, x2v, a2); b2 = fmaf(t1.z, x2v, b2);
        a3 = fmaf(t0.w, x3, a3);  b3 = fmaf(t1.w, x3, b3);
    }

    __shared__ float part[2][4][64];
    part[0][w][d] = (a0 + a1) + (a2 + a3);
    part[1][w][d] = (b0 + b1) + (b2 + b3);
    __syncthreads();

    if (threadIdx.x < 128) {
        const int r = threadIdx.x >> 6;
        const int i = i0 + r;
        float v = (part[r][0][d] + part[r][1][d]) + (part[r][2][d] + part[r][3][d]);

        // alpha = sum of 16 j-tile partials
        float ap = (d < 16) ? alphaPart[(size_t)d * N + i] : 0.f;
#pragma unroll
        for (int off = 1; off < 64; off <<= 1) ap += __shfl_xor(ap, off, 64);

        const float xid = x[(size_t)i * D + d];
        float x2i = xid * xid;
#pragma unroll
        for (int off = 1; off < 64; off <<= 1) x2i += __shfl_xor(x2i, off, 64);
        const float onemx2 = 1.f - x2i;
        const float onemx2c = fmaxf(onemx2, EPSF);
        v = fmaf(ap, xid, v);

        // expmap(v, x_i)
        float vn2 = v * v;
#pragma unroll
        for (int off = 1; off < 64; off <<= 1) vn2 += __shfl_xor(vn2, off, 64);
        const float vn = fmaxf(sqrtf(vn2), EPSF);
        const float arg = vn * rcp_fast(onemx2c);
        const float th = tanhf(arg);
        const float sec = th * rcp_fast(vn) * v;

        // mobius_add(x_i, sec)
        float xy = xid * sec;
        float y2p = sec * sec;
#pragma unroll
        for (int off = 1; off < 64; off <<= 1) {
            xy += __shfl_xor(xy, off, 64);
            y2p += __shfl_xor(y2p, off, 64);
        }
        const float numd = (1.f + 2.f * xy + y2p) * xid + onemx2 * sec;
        const float den2 = fmaxf(fmaf(x2i, y2p, 1.f + 2.f * xy), EPSF);
        out[(size_t)i * D + d] = numd * rcp_fast(den2);
    }
}

extern "C" void kernel_launch(void* const* d_in, const int* in_sizes, int n_in,
                              void* d_out, int out_size, void* d_ws, size_t ws_size,
                              hipStream_t stream) {
    const float* x = (const float*)d_in[0];
    const int* adj = (const int*)d_in[1];
    float* out = (float*)d_out;
    const int N = 1024;

    float* T = (float*)d_ws;                                       // 4 MB
    float* alphaPart = (float*)((char*)d_ws + (size_t)N * N * 4);  // 64 KB

    hipLaunchKernelGGL(pair_kernel, dim3(16, 32), dim3(256), 0, stream, x, adj, T, alphaPart);
    hipLaunchKernelGGL(out_kernel, dim3(N / 2), dim3(256), 0, stream, x, T, alphaPart, out);
}